// Round 1
// baseline (481.413 us; speedup 1.0000x reference)
//
#include <hip/hip_runtime.h>
#include <hip/hip_bf16.h>
#include <stdint.h>

#define N_PTS 100000
#define D     512
#define KDIM  256
#define NCOL  512           // 2*K phi columns (raw || perturbed)
#define NPAD  100096        // 782*128 padded rows for sign buffer
#define NB1   99999         // N-1 crossing positions
#define NW    1563          // ceil(99999/64) u64 words per column

typedef float  f32x4  __attribute__((ext_vector_type(4)));
typedef __bf16 bf16x8 __attribute__((ext_vector_type(8)));

// ---------- K0: build W bf16 [512 rows j][512 cols d] ----------
// row j < 256: theta[j][:] ; row j >= 256: theta[j-256][:] + 0.01*noise[j-256][:]
__global__ void build_w(const float* __restrict__ theta,
                        const float* __restrict__ noise,
                        __bf16* __restrict__ W) {
    int idx = blockIdx.x * 256 + threadIdx.x;   // 0..262143
    int j = idx >> 9;
    int d = idx & 511;
    float v;
    if (j < KDIM) v = theta[j * D + d];
    else          v = theta[(j - KDIM) * D + d] + 0.01f * noise[(j - KDIM) * D + d];
    W[idx] = (__bf16)v;
}

// ---------- K1: bf16 MFMA GEMM -> sign bytes ----------
// C[n_row][j] = sum_d basis[n_row][d] * W[j][d]; store (C<0) as u8 into sgn[NPAD][512].
// 128x128 tile, BK=32, 256 threads (4 waves, 2x2), 4x4 16x16x32 fragments per wave.
// f32->bf16 cast fused into register-staged prefetch.
__launch_bounds__(256, 2)
__global__ void gemm_signs(const float* __restrict__ basis,
                           const __bf16* __restrict__ W,
                           uint8_t* __restrict__ sgn) {
    __shared__ __bf16 As[128 * 32];
    __shared__ __bf16 Bs[128 * 32];

    const int tid  = threadIdx.x;
    const int lane = tid & 63;
    const int wave = tid >> 6;
    const int wrow = wave >> 1;     // 0..1
    const int wcol = wave & 1;      // 0..1
    const int bn = blockIdx.x;      // 0..3   (fastest -> blocks sharing A-tile adjacent)
    const int bm = blockIdx.y;      // 0..781

    // staging: thread t owns LDS row srow (0..127), 16-element half shalf
    const int srow  = tid >> 1;
    const int shalf = tid & 1;
    int agrow = bm * 128 + srow;
    if (agrow > N_PTS - 1) agrow = N_PTS - 1;            // clamp tail rows (values unused)
    const float*  aptr = basis + (size_t)agrow * D + shalf * 16;
    const __bf16* bptr = W + (size_t)(bn * 128 + srow) * D + shalf * 16;

    f32x4 acc[4][4] = {};

    float4 ar[2][4];
    uint4  br[2][2];

    // prefetch kt = 0
    {
        const float4* ap = (const float4*)aptr;
        ar[0][0] = ap[0]; ar[0][1] = ap[1]; ar[0][2] = ap[2]; ar[0][3] = ap[3];
        const uint4* bp = (const uint4*)bptr;
        br[0][0] = bp[0]; br[0][1] = bp[1];
    }

    const int lane16 = lane & 15;
    const int lgrp   = lane >> 4;

    #pragma unroll
    for (int kt = 0; kt < 16; ++kt) {
        const int cur = kt & 1, nxt = cur ^ 1;

        // convert current A regs to bf16 (reg-only; waits on vmcnt here)
        __bf16 abuf[16];
        #pragma unroll
        for (int v = 0; v < 4; ++v) {
            abuf[v * 4 + 0] = (__bf16)ar[cur][v].x;
            abuf[v * 4 + 1] = (__bf16)ar[cur][v].y;
            abuf[v * 4 + 2] = (__bf16)ar[cur][v].z;
            abuf[v * 4 + 3] = (__bf16)ar[cur][v].w;
        }

        __syncthreads();   // prev iteration's LDS reads complete before overwrite
        {
            bf16x8* adst = (bf16x8*)&As[srow * 32 + shalf * 16];
            adst[0] = *(bf16x8*)&abuf[0];
            adst[1] = *(bf16x8*)&abuf[8];
            uint4* bdst = (uint4*)&Bs[srow * 32 + shalf * 16];
            bdst[0] = br[cur][0];
            bdst[1] = br[cur][1];
        }
        // issue next-tile global loads (latency hides under MFMA below)
        if (kt < 15) {
            const float4* ap = (const float4*)(aptr + (size_t)(kt + 1) * 32);
            ar[nxt][0] = ap[0]; ar[nxt][1] = ap[1]; ar[nxt][2] = ap[2]; ar[nxt][3] = ap[3];
            const uint4* bp = (const uint4*)(bptr + (size_t)(kt + 1) * 32);
            br[nxt][0] = bp[0]; br[nxt][1] = bp[1];
        }
        __syncthreads();   // LDS writes visible

        bf16x8 af[4], bfm[4];
        #pragma unroll
        for (int m = 0; m < 4; ++m)
            af[m] = *(bf16x8*)&As[(wrow * 64 + m * 16 + lane16) * 32 + lgrp * 8];
        #pragma unroll
        for (int n = 0; n < 4; ++n)
            bfm[n] = *(bf16x8*)&Bs[(wcol * 64 + n * 16 + lane16) * 32 + lgrp * 8];

        #pragma unroll
        for (int m = 0; m < 4; ++m)
            #pragma unroll
            for (int n = 0; n < 4; ++n)
                acc[m][n] = __builtin_amdgcn_mfma_f32_16x16x32_bf16(af[m], bfm[n], acc[m][n], 0, 0, 0);
    }

    // epilogue: sign bytes. C/D layout: col = lane&15, row = (lane>>4)*4 + reg
    const int col0 = bn * 128 + wcol * 64;
    const int row0 = bm * 128 + wrow * 64;
    #pragma unroll
    for (int m = 0; m < 4; ++m) {
        #pragma unroll
        for (int n = 0; n < 4; ++n) {
            const int col  = col0 + n * 16 + lane16;
            const int rowb = row0 + m * 16 + lgrp * 4;
            #pragma unroll
            for (int r = 0; r < 4; ++r)
                sgn[(size_t)(rowb + r) * NCOL + col] = acc[m][n][r] < 0.0f ? (uint8_t)1 : (uint8_t)0;
        }
    }
}

// ---------- K2: persistence bits, packed along n, column-major words ----------
// maskT[w][j] bit b (n = 64w+b < 99999):
//   (sgn[n][j]^sgn[n+1][j]) & (sgn[n][j+256]^sgn[n+1][j+256])
__global__ void persist_pack(const uint8_t* __restrict__ sgn,
                             uint64_t* __restrict__ maskT) {
    const int w = blockIdx.x;       // 0..1562
    const int j = threadIdx.x;      // 0..255
    const int n0 = w * 64;
    const uint8_t* sr = sgn + j;
    const uint8_t* sp = sgn + j + 256;
    uint8_t r_prev = sr[(size_t)n0 * NCOL];
    uint8_t p_prev = sp[(size_t)n0 * NCOL];
    uint64_t bits = 0;
    int nb = 64;
    if (n0 + 64 > NB1) nb = NB1 - n0;   // last word: 31 valid bits (wave-uniform)
    for (int b = 0; b < nb; ++b) {
        uint8_t r_next = sr[(size_t)(n0 + b + 1) * NCOL];
        uint8_t p_next = sp[(size_t)(n0 + b + 1) * NCOL];
        uint64_t bit = (uint64_t)(((r_prev ^ r_next) & (p_prev ^ p_next)) & 1);
        bits |= bit << b;
        r_prev = r_next; p_prev = p_next;
    }
    maskT[(size_t)w * 256 + j] = bits;
}

// ---------- K3: pairwise AND-popcount ----------
// block i, thread j; maskT[w][i] is wave-uniform (scalar), maskT[w][j] coalesced.
__global__ void pair_popcount(const uint64_t* __restrict__ maskT,
                              float* __restrict__ out) {
    const int i = blockIdx.x;   // 0..255
    const int j = threadIdx.x;  // 0..255
    if (j <= i) return;
    uint32_t sum = 0;
    #pragma unroll 4
    for (int w = 0; w < NW; ++w) {
        uint64_t mi = maskT[(size_t)w * 256 + i];
        uint64_t mj = maskT[(size_t)w * 256 + j];
        sum += (uint32_t)__popcll(mi & mj);
    }
    const size_t idx = (size_t)i * (2 * KDIM - i - 1) / 2 + (size_t)(j - i - 1);
    out[idx] = (float)sum;
}

extern "C" void kernel_launch(void* const* d_in, const int* in_sizes, int n_in,
                              void* d_out, int out_size, void* d_ws, size_t ws_size,
                              hipStream_t stream) {
    const float* theta = (const float*)d_in[0];   // [256,512]
    const float* basis = (const float*)d_in[1];   // [100000,512]
    const float* noise = (const float*)d_in[2];   // [256,512]
    float* out = (float*)d_out;                   // [32640]

    char* ws = (char*)d_ws;
    __bf16*   W     = (__bf16*)ws;                                  // 512*512*2   = 512 KB
    uint8_t*  sgn   = (uint8_t*)(ws + 524288);                      // 100096*512  = 51.25 MB
    uint64_t* maskT = (uint64_t*)(ws + 524288 + (size_t)NPAD * NCOL); // 1563*256*8 = 3.2 MB

    hipLaunchKernelGGL(build_w,       dim3(1024),    dim3(256), 0, stream, theta, noise, W);
    hipLaunchKernelGGL(gemm_signs,    dim3(4, 782),  dim3(256), 0, stream, basis, W, sgn);
    hipLaunchKernelGGL(persist_pack,  dim3(NW),      dim3(256), 0, stream, sgn, maskT);
    hipLaunchKernelGGL(pair_popcount, dim3(KDIM),    dim3(256), 0, stream, maskT, out);
}

// Round 2
// 143.221 us; speedup vs baseline: 3.3613x; 3.3613x over previous
//
#include <hip/hip_runtime.h>
#include <hip/hip_bf16.h>
#include <stdint.h>

#define N_PTS   100000
#define D       512
#define KDIM    256
#define NB1     99999        // N-1 crossing positions
#define NWORDS  1564         // sign words per column: 100096/64
#define NW      1563         // crossing words (ceil(99999/64))
#define GRIDX   3128         // 4 * 782 blocks
#define CHUNK   391          // 3128 / 8 XCDs

typedef float  f32x4  __attribute__((ext_vector_type(4)));
typedef __bf16 bf16x8 __attribute__((ext_vector_type(8)));

// ---------- K0: build W bf16 [512 rows j][512 cols d] ----------
__global__ void build_w(const float* __restrict__ theta,
                        const float* __restrict__ noise,
                        __bf16* __restrict__ W) {
    int idx = blockIdx.x * 256 + threadIdx.x;   // 0..262143
    int j = idx >> 9;
    int d = idx & 511;
    float v;
    if (j < KDIM) v = theta[j * D + d];
    else          v = theta[(j - KDIM) * D + d] + 0.01f * noise[(j - KDIM) * D + d];
    W[idx] = (__bf16)v;
}

// ---------- K1: fused bf16 MFMA GEMM -> packed sign bits ----------
// 128x128 tile, BK=32, 4 waves (2x2), reg-staged f32->bf16 A, raw-barrier
// pipeline (loads stay in flight across barriers), epilogue LDS byte
// transpose + multiply-pack -> sbits[word][col] u64 (bit b = sign of row 64w+b).
__global__ void __launch_bounds__(256)
gemm_signs(const float* __restrict__ basis,
           const __bf16* __restrict__ W,
           uint64_t* __restrict__ sbits) {
    __shared__ char smem[17024];
    __bf16* As = (__bf16*)smem;            // [128][32]
    __bf16* Bs = (__bf16*)(smem + 8192);   // [128][32]

    const int tid  = threadIdx.x;
    const int lane = tid & 63;
    const int wave = tid >> 6;
    const int wrow = wave >> 1;     // 0..1
    const int wcol = wave & 1;      // 0..1

    // XCD-chunk swizzle: phys%8 -> XCD; give each XCD a contiguous lid range
    // so the 4 bn-blocks sharing an A-tile hit the same L2. 3128 = 8*391.
    const int phys = blockIdx.x;
    const int lid  = (phys & 7) * CHUNK + (phys >> 3);
    const int bn   = lid & 3;       // 0..3   column tile
    const int bm   = lid >> 2;      // 0..781 row tile

    // staging: thread owns LDS row srow, 16-element half shalf
    const int srow  = tid >> 1;
    const int shalf = tid & 1;
    int agrow = bm * 128 + srow;
    if (agrow > N_PTS - 1) agrow = N_PTS - 1;        // tail clamp (bits masked later)
    const float*  aptr = basis + (size_t)agrow * D + shalf * 16;
    const __bf16* bptr = W + (size_t)(bn * 128 + srow) * D + shalf * 16;

    f32x4 acc[4][4] = {};
    float4 ra[2][4];
    uint4  rb[2][2];

    // prologue: prefetch kt=0
    {
        const float4* ap = (const float4*)aptr;
        ra[0][0] = ap[0]; ra[0][1] = ap[1]; ra[0][2] = ap[2]; ra[0][3] = ap[3];
        const uint4* bp = (const uint4*)bptr;
        rb[0][0] = bp[0]; rb[0][1] = bp[1];
    }

    const int lane16 = lane & 15;
    const int lgrp   = lane >> 4;
    const int aoff   = (wrow * 64 + lane16) * 32 + lgrp * 8;
    const int boff   = (wcol * 64 + lane16) * 32 + lgrp * 8;

    #pragma unroll
    for (int kt = 0; kt < 16; ++kt) {
        const int cur = kt & 1, nxt = cur ^ 1;

        // issue next-tile global loads FIRST -- they stay in flight across the
        // raw barriers below (no vmcnt(0) drain).
        if (kt < 15) {
            const float4* ap = (const float4*)(aptr + (size_t)(kt + 1) * 32);
            ra[nxt][0] = ap[0]; ra[nxt][1] = ap[1]; ra[nxt][2] = ap[2]; ra[nxt][3] = ap[3];
            const uint4* bp = (const uint4*)(bptr + (size_t)(kt + 1) * 32);
            rb[nxt][0] = bp[0]; rb[nxt][1] = bp[1];
        }

        // convert current A regs to bf16 (compiler waits the right vmcnt here)
        __bf16 abuf[16];
        #pragma unroll
        for (int v = 0; v < 4; ++v) {
            abuf[v * 4 + 0] = (__bf16)ra[cur][v].x;
            abuf[v * 4 + 1] = (__bf16)ra[cur][v].y;
            abuf[v * 4 + 2] = (__bf16)ra[cur][v].z;
            abuf[v * 4 + 3] = (__bf16)ra[cur][v].w;
        }

        __builtin_amdgcn_s_barrier();   // all waves done ds_reading previous tile
        {
            bf16x8* adst = (bf16x8*)&As[srow * 32 + shalf * 16];
            adst[0] = *(bf16x8*)&abuf[0];
            adst[1] = *(bf16x8*)&abuf[8];
            uint4* bdst = (uint4*)&Bs[srow * 32 + shalf * 16];
            bdst[0] = rb[cur][0];
            bdst[1] = rb[cur][1];
        }
        asm volatile("s_waitcnt lgkmcnt(0)" ::: "memory");   // ds_writes landed
        __builtin_amdgcn_s_barrier();
        __builtin_amdgcn_sched_barrier(0);

        bf16x8 af[4], bfm[4];
        #pragma unroll
        for (int m = 0; m < 4; ++m) af[m]  = *(bf16x8*)&As[aoff + m * 512];
        #pragma unroll
        for (int n = 0; n < 4; ++n) bfm[n] = *(bf16x8*)&Bs[boff + n * 512];

        #pragma unroll
        for (int m = 0; m < 4; ++m)
            #pragma unroll
            for (int n = 0; n < 4; ++n)
                acc[m][n] = __builtin_amdgcn_mfma_f32_16x16x32_bf16(af[m], bfm[n], acc[m][n], 0, 0, 0);
    }

    // ---- epilogue: sign bits, LDS transpose, multiply-pack ----
    __builtin_amdgcn_s_barrier();       // all waves finished reading As/Bs
    unsigned char* sb = (unsigned char*)smem;   // [128 cols][132 bytes] (pad kills conflicts)

    // C/D layout: col = lane&15, row = (lane>>4)*4 + reg
    #pragma unroll
    for (int m = 0; m < 4; ++m) {
        #pragma unroll
        for (int n = 0; n < 4; ++n) {
            const int cl  = wcol * 64 + n * 16 + lane16;           // local col 0..127
            const int rw  = wrow * 64 + m * 16 + lgrp * 4;         // local row base
            uint32_t pk = 0;
            #pragma unroll
            for (int r = 0; r < 4; ++r)
                pk |= (acc[m][n][r] < 0.0f ? 1u : 0u) << (8 * r);
            *(uint32_t*)&sb[cl * 132 + rw] = pk;                   // 4 rows as one u32
        }
    }
    asm volatile("s_waitcnt lgkmcnt(0)" ::: "memory");
    __builtin_amdgcn_s_barrier();

    // pack: thread -> (col 0..127, half 0..1); 64 bytes -> u64
    {
        const int col  = tid >> 1;
        const int half = tid & 1;
        const unsigned char* src = &sb[col * 132 + half * 64];
        uint64_t wbits = 0;
        #pragma unroll
        for (int k = 0; k < 16; ++k) {
            uint32_t q  = *(const uint32_t*)&src[4 * k];
            uint32_t p4 = ((q & 0x01010101u) * 0x10204080u) >> 28;  // 4 bytes -> 4 bits
            wbits |= (uint64_t)p4 << (4 * k);
        }
        sbits[(size_t)(bm * 2 + half) * 512 + bn * 128 + col] = wbits;  // coalesced
    }
}

// ---------- K2: crossing masks from sign bits ----------
// maskT[w][j] bit b = (s[n]^s[n+1])_raw & (s[n]^s[n+1])_pert, n = 64w+b
__global__ void crossing_masks(const uint64_t* __restrict__ sbits,
                               uint64_t* __restrict__ maskT) {
    const int w = blockIdx.x;       // 0..1562
    const int j = threadIdx.x;      // 0..255
    uint64_t s0r = sbits[(size_t)w * 512 + j];
    uint64_t s0p = sbits[(size_t)w * 512 + 256 + j];
    uint64_t s1r = sbits[(size_t)(w + 1) * 512 + j];
    uint64_t s1p = sbits[(size_t)(w + 1) * 512 + 256 + j];
    uint64_t cr = s0r ^ ((s0r >> 1) | (s1r << 63));
    uint64_t cp = s0p ^ ((s0p >> 1) | (s1p << 63));
    uint64_t m = cr & cp;
    if (w == NW - 1) m &= 0x7FFFFFFFull;    // 31 valid crossings in last word
    maskT[(size_t)w * 256 + j] = m;
}

// ---------- K3: pairwise AND-popcount ----------
__global__ void zero_out(float* __restrict__ out) {
    int i = blockIdx.x * 256 + threadIdx.x;
    if (i < 32640) out[i] = 0.0f;
}

__global__ void pair_popcount(const uint64_t* __restrict__ maskT,
                              float* __restrict__ out) {
    const int i = blockIdx.x;   // 0..255
    const int c = blockIdx.y;   // 0..3 word chunk
    const int j = threadIdx.x;  // 0..255
    if (j <= i) return;
    int w0 = c * 391;
    int w1 = w0 + 391; if (w1 > NW) w1 = NW;
    uint32_t sum = 0;
    #pragma unroll 4
    for (int w = w0; w < w1; ++w) {
        uint64_t mi = maskT[(size_t)w * 256 + i];   // block-uniform -> scalar
        uint64_t mj = maskT[(size_t)w * 256 + j];   // coalesced
        sum += (uint32_t)__popcll(mi & mj);
    }
    const size_t idx = (size_t)i * (2 * KDIM - i - 1) / 2 + (size_t)(j - i - 1);
    atomicAdd(&out[idx], (float)sum);   // exact-integer f32 adds -> deterministic
}

extern "C" void kernel_launch(void* const* d_in, const int* in_sizes, int n_in,
                              void* d_out, int out_size, void* d_ws, size_t ws_size,
                              hipStream_t stream) {
    const float* theta = (const float*)d_in[0];   // [256,512]
    const float* basis = (const float*)d_in[1];   // [100000,512]
    const float* noise = (const float*)d_in[2];   // [256,512]
    float* out = (float*)d_out;                   // [32640]

    char* ws = (char*)d_ws;
    __bf16*   W     = (__bf16*)ws;                              // 512 KB
    uint64_t* sbits = (uint64_t*)(ws + 524288);                 // 1564*512*8 = 6.41 MB
    uint64_t* maskT = (uint64_t*)(ws + 524288 + (size_t)NWORDS * 512 * 8); // 3.2 MB

    hipLaunchKernelGGL(build_w,        dim3(1024),    dim3(256), 0, stream, theta, noise, W);
    hipLaunchKernelGGL(gemm_signs,     dim3(GRIDX),   dim3(256), 0, stream, basis, W, sbits);
    hipLaunchKernelGGL(crossing_masks, dim3(NW),      dim3(256), 0, stream, sbits, maskT);
    hipLaunchKernelGGL(zero_out,       dim3(128),     dim3(256), 0, stream, out);
    hipLaunchKernelGGL(pair_popcount,  dim3(KDIM, 4), dim3(256), 0, stream, maskT, out);
}